// Round 16
// baseline (986.791 us; speedup 1.0000x reference)
//
#include <hip/hip_runtime.h>
#include <math.h>

#define BB 16
#define NN 4096

typedef float v2f __attribute__((ext_vector_type(2)));

__device__ __forceinline__ v2f pkfma(v2f a, v2f b, v2f c) {
    return __builtin_elementwise_fma(a, b, c);   // -> v_pk_fma_f32 on gfx950
}

__device__ __forceinline__ float sq3(float dx, float dy, float dz) {
    // match numpy: ((dx*dx + dy*dy) + dz*dz), no fma contraction
    return __fadd_rn(__fadd_rn(__fmul_rn(dx, dx), __fmul_rn(dy, dy)), __fmul_rn(dz, dz));
}

// One DPP max step on a packed u64 (non-negative): o = dpp(P); P = max(P,o).
// bound_ctrl=1 -> invalid lanes read 0; 0 is identity for our u64 max.
template<int CTRL, int RMASK>
__device__ __forceinline__ unsigned long long dpp_max_step(unsigned long long P) {
    int lo = __builtin_amdgcn_update_dpp(0, (int)(unsigned)P,        CTRL, RMASK, 0xf, true);
    int hi = __builtin_amdgcn_update_dpp(0, (int)(unsigned)(P >> 32), CTRL, RMASK, 0xf, true);
    unsigned long long o = ((unsigned long long)(unsigned)hi << 32) | (unsigned)lo;
    return (o > P) ? o : P;
}

// Full-wave u64 max via DPP (VALU-latency, no LDS shuffles). Result valid in lane 63.
__device__ __forceinline__ unsigned long long dpp_wave_max_u64(unsigned long long P) {
    P = dpp_max_step<0x111, 0xf>(P);   // row_shr:1
    P = dpp_max_step<0x112, 0xf>(P);   // row_shr:2
    P = dpp_max_step<0x114, 0xf>(P);   // row_shr:4
    P = dpp_max_step<0x118, 0xf>(P);   // row_shr:8
    P = dpp_max_step<0x142, 0xa>(P);   // row_bcast15
    P = dpp_max_step<0x143, 0xc>(P);   // row_bcast31 -> lane 63 has wave max
    return P;
}

__device__ __forceinline__ unsigned long long u64max(unsigned long long a, unsigned long long b) {
    return (a > b) ? a : b;
}

// ---------------- FPS (one block per batch, sequential argmax) ----------------
// r12 body — the EMPIRICAL OPTIMUM at ~306us. Do not change:
//  - TPB=512 (r7: 256=497us; r4/r11: 1024 regressed — barrier skew scales with waves)
//  - scalar sq3 + interleaved argmax compare (r14: packed+scan = +10us, longer chain)
//  - DPP u64 reduce, log-tree slots, no global ops in loop
//  - must run with nothing co-resident (r9: CU sharing ~2x slowdown)
template<int NPTS, int NPOINT, int TPB>
__global__ __launch_bounds__(TPB) void fps_kernel(const float* __restrict__ xyz,
                                                  float* __restrict__ newxyz,
                                                  float* __restrict__ out_t,
                                                  int ts) {
    constexpr int PPT = NPTS / TPB;
    constexpr int NW  = TPB / 64;
    static_assert(NPOINT <= TPB, "far-history latch needs NPOINT <= TPB");
    __shared__ float sx[NPTS], sy[NPTS], sz[NPTS];
    __shared__ __align__(16) unsigned long long slot[2][NW];
    const int b = blockIdx.x;
    const int tid = threadIdx.x;
    const float* base = xyz + (size_t)b * NPTS * 3;
    for (int i = tid; i < NPTS; i += TPB) {
        sx[i] = base[i * 3 + 0];
        sy[i] = base[i * 3 + 1];
        sz[i] = base[i * 3 + 2];
    }
    __syncthreads();
    float px[PPT], py[PPT], pz[PPT], dist[PPT];
#pragma unroll
    for (int k = 0; k < PPT; k++) {
        int p = tid + k * TPB;
        px[k] = sx[p]; py[k] = sy[p]; pz[k] = sz[p];
        dist[k] = 1e10f;
    }
    int far = 0;
    int myfar = 0;
    const int lane = tid & 63, wid = tid >> 6;
    for (int it = 0; it < NPOINT; it++) {
        if (tid == it) myfar = far;          // latch entering-far for the final write
        float fx = sx[far], fy = sy[far], fz = sz[far];
        float bv = -1.0f; int bi = 0;
#pragma unroll
        for (int k = 0; k < PPT; k++) {
            float d = sq3(px[k] - fx, py[k] - fy, pz[k] - fz);
            float nd = fminf(dist[k], d);
            dist[k] = nd;
            if (nd > bv) { bv = nd; bi = tid + k * TPB; }   // strict > keeps smallest k
        }
        unsigned long long P = ((unsigned long long)__float_as_uint(bv) << 32)
                             | (unsigned long long)(~(unsigned)bi & 0xFFFFFFFFull);
        P = dpp_wave_max_u64(P);
        int bufi = it & 1;
        if (lane == 63) slot[bufi][wid] = P;
        __syncthreads();
        // log-tree: all slot loads issued upfront, then pairwise max
        unsigned long long v[NW];
#pragma unroll
        for (int w = 0; w < NW; w++) v[w] = slot[bufi][w];
#pragma unroll
        for (int st = NW / 2; st >= 1; st >>= 1)
#pragma unroll
            for (int w = 0; w < st; w++) v[w] = u64max(v[w], v[w + st]);
        far = (int)(~(unsigned)(v[0] & 0xFFFFFFFFull));
    }
    if (tid < NPOINT) {
        float fx = sx[myfar], fy = sy[myfar], fz = sz[myfar];
        newxyz[((size_t)b * NPOINT + tid) * 3 + 0] = fx;
        newxyz[((size_t)b * NPOINT + tid) * 3 + 1] = fy;
        newxyz[((size_t)b * NPOINT + tid) * 3 + 2] = fz;
        if (out_t) {
            out_t[0 * ts + b * NPOINT + tid] = fx;
            out_t[1 * ts + b * NPOINT + tid] = fy;
            out_t[2 * ts + b * NPOINT + tid] = fz;
        }
    }
}

// ---------------- ball query body: one wave per center, ballot rounds ----------------
template<int NS>
__device__ __forceinline__ void bq_body(const float* __restrict__ pts, int n,
                                        const float* __restrict__ centers, int S,
                                        float r2, int* __restrict__ outidx,
                                        int wave, int lane) {
    int b = wave / S, s = wave % S;
    const float* c = centers + ((size_t)b * S + s) * 3;
    float cx = c[0], cy = c[1], cz = c[2];
    const float* pb = pts + (size_t)b * n * 3;
    int* out = outidx + ((size_t)b * S + s) * NS;
    int total = 0, first = -1;
    int rounds = n >> 6;
    for (int r = 0; r < rounds; r++) {
        int p = (r << 6) + lane;
        float dx = pb[p * 3 + 0] - cx, dy = pb[p * 3 + 1] - cy, dz = pb[p * 3 + 2] - cz;
        float d = sq3(dx, dy, dz);
        bool pred = (d <= r2);
        unsigned long long mask = __ballot(pred);
        if (first < 0 && mask) first = (r << 6) + (__ffsll(mask) - 1);
        if (pred) {
            int rank = total + __popcll(mask & ((1ull << lane) - 1ull));
            if (rank < NS) out[rank] = p;
        }
        total += __popcll(mask);
        if (total >= NS) break;
    }
    for (int j = total + lane; j < NS; j += 64) out[j] = first;
}

// ---------------- fused: fps2 single-wave (blocks 0..15) + ballquery1 (16..1039) ----------------
__global__ __launch_bounds__(512) void bq1_fps2_kernel(const float* __restrict__ points,
                                                       const float* __restrict__ l1x,
                                                       float* __restrict__ l2x,
                                                       float* __restrict__ x3t,
                                                       int* __restrict__ idx1,
                                                       float r2a) {
    __shared__ float sx[512], sy[512], sz[512];
    const int tid = threadIdx.x;
    const int lane = tid & 63, wid = tid >> 6;
    if (blockIdx.x < 16) {
        if (wid != 0) return;    // single-wave fps2; no barriers in this path
        const int b = blockIdx.x;
        const float* base = l1x + (size_t)b * 512 * 3;
        for (int i = lane; i < 512; i += 64) {
            sx[i] = base[i * 3 + 0];
            sy[i] = base[i * 3 + 1];
            sz[i] = base[i * 3 + 2];
        }
        float px[8], py[8], pz[8], dist[8];
#pragma unroll
        for (int k = 0; k < 8; k++) {
            int p = lane + k * 64;
            px[k] = sx[p]; py[k] = sy[p]; pz[k] = sz[p];
            dist[k] = 1e10f;
        }
        int far = 0, myfar0 = 0, myfar1 = 0;
        for (int it = 0; it < 128; it++) {
            if (lane == it) myfar0 = far;
            if (lane == it - 64) myfar1 = far;
            float fx = sx[far], fy = sy[far], fz = sz[far];
            float bv = -1.0f; int bi = 0;
#pragma unroll
            for (int k = 0; k < 8; k++) {
                float d = sq3(px[k] - fx, py[k] - fy, pz[k] - fz);
                float nd = fminf(dist[k], d);
                dist[k] = nd;
                if (nd > bv) { bv = nd; bi = lane + k * 64; }
            }
            unsigned long long P = ((unsigned long long)__float_as_uint(bv) << 32)
                                 | (unsigned long long)(~(unsigned)bi & 0xFFFFFFFFull);
            P = dpp_wave_max_u64(P);
            unsigned lo = (unsigned)__builtin_amdgcn_readlane((int)(unsigned)P, 63);
            far = (int)(~lo);          // idx was stored as ~idx in low 32
        }
        {
            int s0 = lane, s1 = lane + 64;
            float a = sx[myfar0], c1 = sy[myfar0], c2 = sz[myfar0];
            l2x[((size_t)b * 128 + s0) * 3 + 0] = a;
            l2x[((size_t)b * 128 + s0) * 3 + 1] = c1;
            l2x[((size_t)b * 128 + s0) * 3 + 2] = c2;
            x3t[0 * 2048 + b * 128 + s0] = a;
            x3t[1 * 2048 + b * 128 + s0] = c1;
            x3t[2 * 2048 + b * 128 + s0] = c2;
            float d = sx[myfar1], e = sy[myfar1], f = sz[myfar1];
            l2x[((size_t)b * 128 + s1) * 3 + 0] = d;
            l2x[((size_t)b * 128 + s1) * 3 + 1] = e;
            l2x[((size_t)b * 128 + s1) * 3 + 2] = f;
            x3t[0 * 2048 + b * 128 + s1] = d;
            x3t[1 * 2048 + b * 128 + s1] = e;
            x3t[2 * 2048 + b * 128 + s1] = f;
        }
    } else {
        int wave = (blockIdx.x - 16) * 8 + wid;   // 1024 blocks x 8 waves = 8192
        bq_body<32>(points, 4096, l1x, 512, r2a, idx1, wave, lane);
    }
}

// ---------------- fused: ballquery2 (blocks 0..2047) + SA1 (blocks 2048..6143) ----------------
__global__ __launch_bounds__(64, 2) void sa1_bq2_kernel(const float* __restrict__ xyz, const float* __restrict__ l1x,
                                                 const int* __restrict__ idx1,
                                                 const float* __restrict__ l2x, int* __restrict__ idx2, float r2b,
                                                 const float* __restrict__ W1, const float* __restrict__ B1,
                                                 const float* __restrict__ W2, const float* __restrict__ B2,
                                                 const float* __restrict__ W3, const float* __restrict__ B3,
                                                 float* __restrict__ l1f) {
    __shared__ float ht[64 * 64];
    int lane = threadIdx.x;
    if (blockIdx.x < 2048) {
        bq_body<64>(l1x, 512, l2x, 128, r2b, idx2, blockIdx.x, lane);
        return;
    }
    int blk = blockIdx.x - 2048;
    int b = blk >> 8;
    int s = ((blk & 255) << 1) | (lane >> 5);
    int nn = lane & 31;
    int center = b * 512 + s;
    int ii = idx1[center * 32 + nn];
    float px = xyz[((size_t)b * NN + ii) * 3 + 0] - l1x[(size_t)center * 3 + 0];
    float py = xyz[((size_t)b * NN + ii) * 3 + 1] - l1x[(size_t)center * 3 + 1];
    float pz = xyz[((size_t)b * NN + ii) * 3 + 2] - l1x[(size_t)center * 3 + 2];
#pragma unroll
    for (int c = 0; c < 64; c++)
        ht[c * 64 + lane] = fmaxf(B1[c] + px * W1[c] + py * W1[64 + c] + pz * W1[128 + c], 0.0f);
    __syncthreads();
    v2f h2[32];
    const v2f* B2v = (const v2f*)B2;
#pragma unroll
    for (int c = 0; c < 32; c++) h2[c] = B2v[c];
    for (int k = 0; k < 64; k++) {
        float xk = ht[k * 64 + lane];
        v2f xk2 = {xk, xk};
        const v2f* wr = (const v2f*)(W2 + k * 64);
#pragma unroll
        for (int c = 0; c < 32; c++) h2[c] = pkfma(xk2, wr[c], h2[c]);
    }
    __syncthreads();
#pragma unroll
    for (int c = 0; c < 32; c++) {
        ht[(2 * c + 0) * 64 + lane] = fmaxf(h2[c].x, 0.0f);
        ht[(2 * c + 1) * 64 + lane] = fmaxf(h2[c].y, 0.0f);
    }
    __syncthreads();
#pragma unroll
    for (int half = 0; half < 2; half++) {
        v2f o[32];
        const v2f* B3v = (const v2f*)(B3 + half * 64);
#pragma unroll
        for (int j = 0; j < 32; j++) o[j] = B3v[j];
        for (int k = 0; k < 64; k++) {
            float xk = ht[k * 64 + lane];
            v2f xk2 = {xk, xk};
            const v2f* wr = (const v2f*)(W3 + k * 128 + half * 64);
#pragma unroll
            for (int j = 0; j < 32; j++) o[j] = pkfma(xk2, wr[j], o[j]);
        }
#pragma unroll
        for (int j = 0; j < 32; j++) {
            float va = fmaxf(o[j].x, 0.0f);
            float vb = fmaxf(o[j].y, 0.0f);
#pragma unroll
            for (int m = 16; m >= 1; m >>= 1) {
                va = fmaxf(va, __shfl_xor(va, m));
                vb = fmaxf(vb, __shfl_xor(vb, m));
            }
            o[j].x = va; o[j].y = vb;
        }
        if (nn == 0) {
#pragma unroll
            for (int j = 0; j < 32; j++) {
                l1f[(size_t)center * 128 + half * 64 + 2 * j + 0] = o[j].x;
                l1f[(size_t)center * 128 + half * 64 + 2 * j + 1] = o[j].y;
            }
        }
    }
}

// ---------------- SA2 MLP: 131->128->128->256, max over 64 nbrs, packed fp32 ----------------
// r16: 512 threads = 8 waves x 16 channels (extends r5's winning occupancy lever:
// 2->4 waves was -200us; 8 waves fills the 32-wave/CU cap at 32KB LDS and halves
// the per-wave s_load weight burst again). unroll 2 kept (r14 tail win).
__global__ __launch_bounds__(512, 2) void sa2_kernel(const float* __restrict__ l1x, const float* __restrict__ l2x,
                                                  const float* __restrict__ l1f, const int* __restrict__ idx2,
                                                  const float* __restrict__ W1, const float* __restrict__ B1,
                                                  const float* __restrict__ W2, const float* __restrict__ B2,
                                                  const float* __restrict__ W3, const float* __restrict__ B3,
                                                  float* __restrict__ x3t) {
    __shared__ float ht[128 * 64];
    int tid = threadIdx.x;
    int w = __builtin_amdgcn_readfirstlane(tid >> 6);   // 0..7, wave-uniform -> SGPR
    int lane = tid & 63;
    int b = blockIdx.x >> 7, s = blockIdx.x & 127;
    int center = b * 128 + s;
    int ii = idx2[center * 64 + lane];
    float cx = l2x[(size_t)center * 3 + 0], cy = l2x[(size_t)center * 3 + 1], cz = l2x[(size_t)center * 3 + 2];
    const float* pr = l1x + ((size_t)b * 512 + ii) * 3;
    float px = pr[0] - cx, py = pr[1] - cy, pz = pr[2] - cz;
    const float4* frow = (const float4*)(l1f + ((size_t)b * 512 + ii) * 128);
    // layer 1: 16 channels per wave = 8 v2f
    v2f h[8];
    {
        const v2f* B1v = (const v2f*)(B1 + w * 16);
        const v2f* w1a = (const v2f*)(W1 + 0 * 128 + w * 16);
        const v2f* w1b = (const v2f*)(W1 + 1 * 128 + w * 16);
        const v2f* w1c = (const v2f*)(W1 + 2 * 128 + w * 16);
        v2f px2 = {px, px}, py2 = {py, py}, pz2 = {pz, pz};
#pragma unroll
        for (int j = 0; j < 8; j++)
            h[j] = pkfma(pz2, w1c[j], pkfma(py2, w1b[j], pkfma(px2, w1a[j], B1v[j])));
    }
#pragma unroll 2
    for (int k4 = 0; k4 < 32; k4++) {
        float4 f = frow[k4];
        const v2f* wr = (const v2f*)(W1 + (3 + k4 * 4) * 128 + w * 16);   // row stride 128 floats = 64 v2f
        v2f fx2 = {f.x, f.x}, fy2 = {f.y, f.y}, fz2 = {f.z, f.z}, fw2 = {f.w, f.w};
#pragma unroll
        for (int j = 0; j < 8; j++) {
            h[j] = pkfma(fx2, wr[j], h[j]);
            h[j] = pkfma(fy2, wr[64 + j], h[j]);
            h[j] = pkfma(fz2, wr[128 + j], h[j]);
            h[j] = pkfma(fw2, wr[192 + j], h[j]);
        }
    }
#pragma unroll
    for (int j = 0; j < 8; j++) {
        ht[(w * 16 + 2 * j + 0) * 64 + lane] = fmaxf(h[j].x, 0.0f);
        ht[(w * 16 + 2 * j + 1) * 64 + lane] = fmaxf(h[j].y, 0.0f);
    }
    __syncthreads();
    // layer 2: 16 channels per wave
    v2f h2[8];
    {
        const v2f* B2v = (const v2f*)(B2 + w * 16);
#pragma unroll
        for (int j = 0; j < 8; j++) h2[j] = B2v[j];
    }
#pragma unroll 2
    for (int k = 0; k < 128; k++) {
        float xk = ht[k * 64 + lane];
        v2f xk2 = {xk, xk};
        const v2f* wr = (const v2f*)(W2 + k * 128 + w * 16);
#pragma unroll
        for (int j = 0; j < 8; j++) h2[j] = pkfma(xk2, wr[j], h2[j]);
    }
    __syncthreads();
#pragma unroll
    for (int j = 0; j < 8; j++) {
        ht[(w * 16 + 2 * j + 0) * 64 + lane] = fmaxf(h2[j].x, 0.0f);
        ht[(w * 16 + 2 * j + 1) * 64 + lane] = fmaxf(h2[j].y, 0.0f);
    }
    __syncthreads();
    // layer 3: 32 channels per wave, two 16-channel passes
#pragma unroll
    for (int half = 0; half < 2; half++) {
        v2f o[8];
        const v2f* B3v = (const v2f*)(B3 + w * 32 + half * 16);
#pragma unroll
        for (int j = 0; j < 8; j++) o[j] = B3v[j];
#pragma unroll 2
        for (int k = 0; k < 128; k++) {
            float xk = ht[k * 64 + lane];
            v2f xk2 = {xk, xk};
            const v2f* wr = (const v2f*)(W3 + k * 256 + w * 32 + half * 16);
#pragma unroll
            for (int j = 0; j < 8; j++) o[j] = pkfma(xk2, wr[j], o[j]);
        }
#pragma unroll
        for (int j = 0; j < 8; j++) {
            float va = fmaxf(o[j].x, 0.0f);
            float vb = fmaxf(o[j].y, 0.0f);
#pragma unroll
            for (int m = 32; m >= 1; m >>= 1) {
                va = fmaxf(va, __shfl_xor(va, m));
                vb = fmaxf(vb, __shfl_xor(vb, m));
            }
            o[j].x = va; o[j].y = vb;
        }
        if (lane == 0) {
#pragma unroll
            for (int j = 0; j < 8; j++) {
                x3t[(size_t)(3 + w * 32 + half * 16 + 2 * j + 0) * 2048 + center] = o[j].x;
                x3t[(size_t)(3 + w * 32 + half * 16 + 2 * j + 1) * 2048 + center] = o[j].y;
            }
        }
    }
}

// ---------------- transposed GEMM body for SA3 (packed fp32) ----------------
template<int K, int COUT, int CPT, bool MAXOUT>
__device__ __forceinline__ void gemm_t_body(const float* __restrict__ in_t,
                                            const float* __restrict__ W,
                                            const float* __restrict__ bias,
                                            float* __restrict__ outp,
                                            int bid, int lane) {
    int rw = bid & 31, cg = bid >> 5;
    int row = rw * 64 + lane;
    int cbase = cg * CPT;
    v2f acc[CPT / 2];
    const v2f* bv = (const v2f*)(bias + cbase);
#pragma unroll
    for (int j = 0; j < CPT / 2; j++) acc[j] = bv[j];
    for (int k = 0; k < K; k++) {
        float xk = in_t[(size_t)k * 2048 + row];
        v2f xk2 = {xk, xk};
        const v2f* wr = (const v2f*)(W + (size_t)k * COUT + cbase);
#pragma unroll
        for (int j = 0; j < CPT / 2; j++) acc[j] = pkfma(xk2, wr[j], acc[j]);
    }
    if (MAXOUT) {
        int b = row >> 7;
#pragma unroll
        for (int j = 0; j < CPT / 2; j++) {
            float va = fmaxf(acc[j].x, 0.0f);
            float vb = fmaxf(acc[j].y, 0.0f);
#pragma unroll
            for (int m = 32; m >= 1; m >>= 1) {
                va = fmaxf(va, __shfl_xor(va, m));
                vb = fmaxf(vb, __shfl_xor(vb, m));
            }
            if (lane == 0) {
                atomicMax((int*)(outp + (size_t)b * 1024 + cbase + 2 * j + 0), __float_as_int(va));
                atomicMax((int*)(outp + (size_t)b * 1024 + cbase + 2 * j + 1), __float_as_int(vb));
            }
        }
    } else {
#pragma unroll
        for (int j = 0; j < CPT / 2; j++) {
            outp[(size_t)(cbase + 2 * j + 0) * 2048 + row] = fmaxf(acc[j].x, 0.0f);
            outp[(size_t)(cbase + 2 * j + 1) * 2048 + row] = fmaxf(acc[j].y, 0.0f);
        }
    }
}

template<int K, int COUT, int CPT, bool MAXOUT>
__global__ __launch_bounds__(64, 4) void gemm_t_kernel(const float* __restrict__ in_t,
                                                    const float* __restrict__ W,
                                                    const float* __restrict__ bias,
                                                    float* __restrict__ outp) {
    gemm_t_body<K, COUT, CPT, MAXOUT>(in_t, W, bias, outp, blockIdx.x, threadIdx.x);
}

// gemm1 CPT=8 (blocks 0..1023) + zero-init of g (blocks 1024..1279)
__global__ __launch_bounds__(64, 4) void gemm1_zerog_kernel(const float* __restrict__ in_t,
                                                            const float* __restrict__ W,
                                                            const float* __restrict__ bias,
                                                            float* __restrict__ outp,
                                                            float* __restrict__ g) {
    if (blockIdx.x < 1024) {
        gemm_t_body<259, 256, 8, false>(in_t, W, bias, outp, blockIdx.x, threadIdx.x);
    } else {
        g[(blockIdx.x - 1024) * 64 + threadIdx.x] = 0.0f;
    }
}

// ---------------- FC heads ----------------
__global__ __launch_bounds__(512) void head_kernel(const float* __restrict__ g,
                                                   const float* __restrict__ lw1, const float* __restrict__ lb1,
                                                   const float* __restrict__ lw2, const float* __restrict__ lb2,
                                                   const float* __restrict__ fw1, const float* __restrict__ fb1,
                                                   const float* __restrict__ fw2, const float* __restrict__ fb2,
                                                   const float* __restrict__ pm, const float* __restrict__ ps,
                                                   const float* __restrict__ rm, const float* __restrict__ rs,
                                                   float* __restrict__ out) {
    __shared__ float gl[1024], a1[256], f1[512];
    int b = blockIdx.x, t = threadIdx.x;
    for (int i = t; i < 1024; i += 512) gl[i] = g[b * 1024 + i];
    __syncthreads();
    {
        float acc = fb1[t];
        for (int k = 0; k < 1024; k++) acc += gl[k] * fw1[k * 512 + t];
        f1[t] = fmaxf(acc, 0.0f);
    }
    if (t < 256) {
        float acc = lb1[t];
        for (int k = 0; k < 1024; k++) acc += gl[k] * lw1[k * 256 + t];
        a1[t] = fmaxf(acc, 0.0f);
    }
    __syncthreads();
    if (t < 2) {
        float z = lb2[t];
        for (int k = 0; k < 256; k++) z += a1[k] * lw2[k * 2 + t];
        out[b * 20 + t] = 1.0f / (1.0f + expf(-z));
    } else if (t < 20) {
        int i = t - 2;
        float z = fb2[i];
        for (int k = 0; k < 512; k++) z += f1[k] * fw2[k * 18 + i];
        float sc, mn;
        if (i < 3)       { sc = ps[i];      mn = pm[i]; }
        else if (i < 9)  { sc = rs[i - 3];  mn = rm[i - 3]; }
        else if (i < 12) { sc = ps[i - 9];  mn = pm[i - 9]; }
        else             { sc = rs[i - 12]; mn = rm[i - 12]; }
        out[b * 20 + t] = z * sc + mn;
    }
}

static inline size_t align256(size_t x) { return (x + 255) & ~(size_t)255; }

extern "C" void kernel_launch(void* const* d_in, const int* in_sizes, int n_in,
                              void* d_out, int out_size, void* d_ws, size_t ws_size,
                              hipStream_t stream) {
    const float* points = (const float*)d_in[0];
    const float* w10 = (const float*)d_in[1];  const float* b10 = (const float*)d_in[2];
    const float* w11 = (const float*)d_in[3];  const float* b11 = (const float*)d_in[4];
    const float* w12 = (const float*)d_in[5];  const float* b12 = (const float*)d_in[6];
    const float* w20 = (const float*)d_in[7];  const float* b20 = (const float*)d_in[8];
    const float* w21 = (const float*)d_in[9];  const float* b21 = (const float*)d_in[10];
    const float* w22 = (const float*)d_in[11]; const float* b22 = (const float*)d_in[12];
    const float* w30 = (const float*)d_in[13]; const float* b30 = (const float*)d_in[14];
    const float* w31 = (const float*)d_in[15]; const float* b31 = (const float*)d_in[16];
    const float* w32 = (const float*)d_in[17]; const float* b32 = (const float*)d_in[18];
    const float* lw1 = (const float*)d_in[19]; const float* lb1 = (const float*)d_in[20];
    const float* lw2 = (const float*)d_in[21]; const float* lb2 = (const float*)d_in[22];
    const float* fw1 = (const float*)d_in[23]; const float* fb1 = (const float*)d_in[24];
    const float* fw2 = (const float*)d_in[25]; const float* fb2 = (const float*)d_in[26];
    const float* pm  = (const float*)d_in[27]; const float* ps  = (const float*)d_in[28];
    const float* rm  = (const float*)d_in[29]; const float* rs  = (const float*)d_in[30];
    float* out = (float*)d_out;

    char* p = (char*)d_ws;
    float* l1x  = (float*)p; p += align256((size_t)BB * 512 * 3 * 4);
    int*   idx1 = (int*)p;   p += align256((size_t)BB * 512 * 32 * 4);
    float* l1f  = (float*)p; p += align256((size_t)BB * 512 * 128 * 4);
    float* l2x  = (float*)p; p += align256((size_t)BB * 128 * 3 * 4);
    int*   idx2 = (int*)p;   p += align256((size_t)BB * 128 * 64 * 4);
    float* x3t  = (float*)p; p += align256((size_t)259 * 2048 * 4);
    float* h1t  = (float*)p; p += align256((size_t)256 * 2048 * 4);
    float* h2t  = (float*)p; p += align256((size_t)512 * 2048 * 4);
    float* g    = (float*)p; p += align256((size_t)BB * 1024 * 4);

    const float R2A = (float)(0.2 * 0.2);
    const float R2B = (float)(0.4 * 0.4);

    fps_kernel<4096, 512, 512><<<BB, 512, 0, stream>>>(points, l1x, (float*)nullptr, 0);
    bq1_fps2_kernel<<<1040, 512, 0, stream>>>(points, l1x, l2x, x3t, idx1, R2A);
    sa1_bq2_kernel<<<6144, 64, 0, stream>>>(points, l1x, idx1, l2x, idx2, R2B,
                                            w10, b10, w11, b11, w12, b12, l1f);
    sa2_kernel<<<2048, 512, 0, stream>>>(l1x, l2x, l1f, idx2, w20, b20, w21, b21, w22, b22, x3t);
    gemm1_zerog_kernel<<<1280, 64, 0, stream>>>(x3t, w30, b30, h1t, g);
    gemm_t_kernel<256, 512, 8, false><<<2048, 64, 0, stream>>>(h1t, w31, b31, h2t);
    gemm_t_kernel<512, 1024, 8, true><<<4096, 64, 0, stream>>>(h2t, w32, b32, g);
    head_kernel<<<BB, 512, 0, stream>>>(g, lw1, lb1, lw2, lb2, fw1, fb1, fw2, fb2, pm, ps, rm, rs, out);
}

// Round 17
// 954.353 us; speedup vs baseline: 1.0340x; 1.0340x over previous
//
#include <hip/hip_runtime.h>
#include <math.h>

#define BB 16
#define NN 4096

typedef float v2f __attribute__((ext_vector_type(2)));

__device__ __forceinline__ v2f pkfma(v2f a, v2f b, v2f c) {
    return __builtin_elementwise_fma(a, b, c);   // -> v_pk_fma_f32 on gfx950
}

__device__ __forceinline__ float sq3(float dx, float dy, float dz) {
    // match numpy: ((dx*dx + dy*dy) + dz*dz), no fma contraction
    return __fadd_rn(__fadd_rn(__fmul_rn(dx, dx), __fmul_rn(dy, dy)), __fmul_rn(dz, dz));
}

// One DPP max step on a packed u64 (non-negative): o = dpp(P); P = max(P,o).
// bound_ctrl=1 -> invalid lanes read 0; 0 is identity for our u64 max.
template<int CTRL, int RMASK>
__device__ __forceinline__ unsigned long long dpp_max_step(unsigned long long P) {
    int lo = __builtin_amdgcn_update_dpp(0, (int)(unsigned)P,        CTRL, RMASK, 0xf, true);
    int hi = __builtin_amdgcn_update_dpp(0, (int)(unsigned)(P >> 32), CTRL, RMASK, 0xf, true);
    unsigned long long o = ((unsigned long long)(unsigned)hi << 32) | (unsigned)lo;
    return (o > P) ? o : P;
}

// Full-wave u64 max via DPP (VALU-latency, no LDS shuffles). Result valid in lane 63.
__device__ __forceinline__ unsigned long long dpp_wave_max_u64(unsigned long long P) {
    P = dpp_max_step<0x111, 0xf>(P);   // row_shr:1
    P = dpp_max_step<0x112, 0xf>(P);   // row_shr:2
    P = dpp_max_step<0x114, 0xf>(P);   // row_shr:4
    P = dpp_max_step<0x118, 0xf>(P);   // row_shr:8
    P = dpp_max_step<0x142, 0xa>(P);   // row_bcast15
    P = dpp_max_step<0x143, 0xc>(P);   // row_bcast31 -> lane 63 has wave max
    return P;
}

__device__ __forceinline__ unsigned long long u64max(unsigned long long a, unsigned long long b) {
    return (a > b) ? a : b;
}

// ---------------- FPS (one block per batch, sequential argmax) ----------------
// r12 body — the EMPIRICAL OPTIMUM at ~306us. Do not change:
//  - TPB=512 (r7: 256=497us; r4/r11: 1024 regressed — barrier skew scales with waves)
//  - scalar sq3 + interleaved argmax compare (r14: packed+scan = +10us, longer chain)
//  - DPP u64 reduce, log-tree slots, no global ops in loop
//  - must run with nothing co-resident (r9: CU sharing ~2x slowdown)
template<int NPTS, int NPOINT, int TPB>
__global__ __launch_bounds__(TPB) void fps_kernel(const float* __restrict__ xyz,
                                                  float* __restrict__ newxyz,
                                                  float* __restrict__ out_t,
                                                  int ts) {
    constexpr int PPT = NPTS / TPB;
    constexpr int NW  = TPB / 64;
    static_assert(NPOINT <= TPB, "far-history latch needs NPOINT <= TPB");
    __shared__ float sx[NPTS], sy[NPTS], sz[NPTS];
    __shared__ __align__(16) unsigned long long slot[2][NW];
    const int b = blockIdx.x;
    const int tid = threadIdx.x;
    const float* base = xyz + (size_t)b * NPTS * 3;
    for (int i = tid; i < NPTS; i += TPB) {
        sx[i] = base[i * 3 + 0];
        sy[i] = base[i * 3 + 1];
        sz[i] = base[i * 3 + 2];
    }
    __syncthreads();
    float px[PPT], py[PPT], pz[PPT], dist[PPT];
#pragma unroll
    for (int k = 0; k < PPT; k++) {
        int p = tid + k * TPB;
        px[k] = sx[p]; py[k] = sy[p]; pz[k] = sz[p];
        dist[k] = 1e10f;
    }
    int far = 0;
    int myfar = 0;
    const int lane = tid & 63, wid = tid >> 6;
    for (int it = 0; it < NPOINT; it++) {
        if (tid == it) myfar = far;          // latch entering-far for the final write
        float fx = sx[far], fy = sy[far], fz = sz[far];
        float bv = -1.0f; int bi = 0;
#pragma unroll
        for (int k = 0; k < PPT; k++) {
            float d = sq3(px[k] - fx, py[k] - fy, pz[k] - fz);
            float nd = fminf(dist[k], d);
            dist[k] = nd;
            if (nd > bv) { bv = nd; bi = tid + k * TPB; }   // strict > keeps smallest k
        }
        unsigned long long P = ((unsigned long long)__float_as_uint(bv) << 32)
                             | (unsigned long long)(~(unsigned)bi & 0xFFFFFFFFull);
        P = dpp_wave_max_u64(P);
        int bufi = it & 1;
        if (lane == 63) slot[bufi][wid] = P;
        __syncthreads();
        // log-tree: all slot loads issued upfront, then pairwise max
        unsigned long long v[NW];
#pragma unroll
        for (int w = 0; w < NW; w++) v[w] = slot[bufi][w];
#pragma unroll
        for (int st = NW / 2; st >= 1; st >>= 1)
#pragma unroll
            for (int w = 0; w < st; w++) v[w] = u64max(v[w], v[w + st]);
        far = (int)(~(unsigned)(v[0] & 0xFFFFFFFFull));
    }
    if (tid < NPOINT) {
        float fx = sx[myfar], fy = sy[myfar], fz = sz[myfar];
        newxyz[((size_t)b * NPOINT + tid) * 3 + 0] = fx;
        newxyz[((size_t)b * NPOINT + tid) * 3 + 1] = fy;
        newxyz[((size_t)b * NPOINT + tid) * 3 + 2] = fz;
        if (out_t) {
            out_t[0 * ts + b * NPOINT + tid] = fx;
            out_t[1 * ts + b * NPOINT + tid] = fy;
            out_t[2 * ts + b * NPOINT + tid] = fz;
        }
    }
}

// ---------------- ball query body: one wave per center, ballot rounds ----------------
template<int NS>
__device__ __forceinline__ void bq_body(const float* __restrict__ pts, int n,
                                        const float* __restrict__ centers, int S,
                                        float r2, int* __restrict__ outidx,
                                        int wave, int lane) {
    int b = wave / S, s = wave % S;
    const float* c = centers + ((size_t)b * S + s) * 3;
    float cx = c[0], cy = c[1], cz = c[2];
    const float* pb = pts + (size_t)b * n * 3;
    int* out = outidx + ((size_t)b * S + s) * NS;
    int total = 0, first = -1;
    int rounds = n >> 6;
    for (int r = 0; r < rounds; r++) {
        int p = (r << 6) + lane;
        float dx = pb[p * 3 + 0] - cx, dy = pb[p * 3 + 1] - cy, dz = pb[p * 3 + 2] - cz;
        float d = sq3(dx, dy, dz);
        bool pred = (d <= r2);
        unsigned long long mask = __ballot(pred);
        if (first < 0 && mask) first = (r << 6) + (__ffsll(mask) - 1);
        if (pred) {
            int rank = total + __popcll(mask & ((1ull << lane) - 1ull));
            if (rank < NS) out[rank] = p;
        }
        total += __popcll(mask);
        if (total >= NS) break;
    }
    for (int j = total + lane; j < NS; j += 64) out[j] = first;
}

// ---------------- fused: fps2 single-wave (blocks 0..15) + ballquery1 (16..1039) ----------------
__global__ __launch_bounds__(512) void bq1_fps2_kernel(const float* __restrict__ points,
                                                       const float* __restrict__ l1x,
                                                       float* __restrict__ l2x,
                                                       float* __restrict__ x3t,
                                                       int* __restrict__ idx1,
                                                       float r2a) {
    __shared__ float sx[512], sy[512], sz[512];
    const int tid = threadIdx.x;
    const int lane = tid & 63, wid = tid >> 6;
    if (blockIdx.x < 16) {
        if (wid != 0) return;    // single-wave fps2; no barriers in this path
        const int b = blockIdx.x;
        const float* base = l1x + (size_t)b * 512 * 3;
        for (int i = lane; i < 512; i += 64) {
            sx[i] = base[i * 3 + 0];
            sy[i] = base[i * 3 + 1];
            sz[i] = base[i * 3 + 2];
        }
        float px[8], py[8], pz[8], dist[8];
#pragma unroll
        for (int k = 0; k < 8; k++) {
            int p = lane + k * 64;
            px[k] = sx[p]; py[k] = sy[p]; pz[k] = sz[p];
            dist[k] = 1e10f;
        }
        int far = 0, myfar0 = 0, myfar1 = 0;
        for (int it = 0; it < 128; it++) {
            if (lane == it) myfar0 = far;
            if (lane == it - 64) myfar1 = far;
            float fx = sx[far], fy = sy[far], fz = sz[far];
            float bv = -1.0f; int bi = 0;
#pragma unroll
            for (int k = 0; k < 8; k++) {
                float d = sq3(px[k] - fx, py[k] - fy, pz[k] - fz);
                float nd = fminf(dist[k], d);
                dist[k] = nd;
                if (nd > bv) { bv = nd; bi = lane + k * 64; }
            }
            unsigned long long P = ((unsigned long long)__float_as_uint(bv) << 32)
                                 | (unsigned long long)(~(unsigned)bi & 0xFFFFFFFFull);
            P = dpp_wave_max_u64(P);
            unsigned lo = (unsigned)__builtin_amdgcn_readlane((int)(unsigned)P, 63);
            far = (int)(~lo);          // idx was stored as ~idx in low 32
        }
        {
            int s0 = lane, s1 = lane + 64;
            float a = sx[myfar0], c1 = sy[myfar0], c2 = sz[myfar0];
            l2x[((size_t)b * 128 + s0) * 3 + 0] = a;
            l2x[((size_t)b * 128 + s0) * 3 + 1] = c1;
            l2x[((size_t)b * 128 + s0) * 3 + 2] = c2;
            x3t[0 * 2048 + b * 128 + s0] = a;
            x3t[1 * 2048 + b * 128 + s0] = c1;
            x3t[2 * 2048 + b * 128 + s0] = c2;
            float d = sx[myfar1], e = sy[myfar1], f = sz[myfar1];
            l2x[((size_t)b * 128 + s1) * 3 + 0] = d;
            l2x[((size_t)b * 128 + s1) * 3 + 1] = e;
            l2x[((size_t)b * 128 + s1) * 3 + 2] = f;
            x3t[0 * 2048 + b * 128 + s1] = d;
            x3t[1 * 2048 + b * 128 + s1] = e;
            x3t[2 * 2048 + b * 128 + s1] = f;
        }
    } else {
        int wave = (blockIdx.x - 16) * 8 + wid;   // 1024 blocks x 8 waves = 8192
        bq_body<32>(points, 4096, l1x, 512, r2a, idx1, wave, lane);
    }
}

// ---------------- fused: ballquery2 (blocks 0..2047) + SA1 (blocks 2048..6143) ----------------
__global__ __launch_bounds__(64, 2) void sa1_bq2_kernel(const float* __restrict__ xyz, const float* __restrict__ l1x,
                                                 const int* __restrict__ idx1,
                                                 const float* __restrict__ l2x, int* __restrict__ idx2, float r2b,
                                                 const float* __restrict__ W1, const float* __restrict__ B1,
                                                 const float* __restrict__ W2, const float* __restrict__ B2,
                                                 const float* __restrict__ W3, const float* __restrict__ B3,
                                                 float* __restrict__ l1f) {
    __shared__ float ht[64 * 64];
    int lane = threadIdx.x;
    if (blockIdx.x < 2048) {
        bq_body<64>(l1x, 512, l2x, 128, r2b, idx2, blockIdx.x, lane);
        return;
    }
    int blk = blockIdx.x - 2048;
    int b = blk >> 8;
    int s = ((blk & 255) << 1) | (lane >> 5);
    int nn = lane & 31;
    int center = b * 512 + s;
    int ii = idx1[center * 32 + nn];
    float px = xyz[((size_t)b * NN + ii) * 3 + 0] - l1x[(size_t)center * 3 + 0];
    float py = xyz[((size_t)b * NN + ii) * 3 + 1] - l1x[(size_t)center * 3 + 1];
    float pz = xyz[((size_t)b * NN + ii) * 3 + 2] - l1x[(size_t)center * 3 + 2];
#pragma unroll
    for (int c = 0; c < 64; c++)
        ht[c * 64 + lane] = fmaxf(B1[c] + px * W1[c] + py * W1[64 + c] + pz * W1[128 + c], 0.0f);
    __syncthreads();
    v2f h2[32];
    const v2f* B2v = (const v2f*)B2;
#pragma unroll
    for (int c = 0; c < 32; c++) h2[c] = B2v[c];
    for (int k = 0; k < 64; k++) {
        float xk = ht[k * 64 + lane];
        v2f xk2 = {xk, xk};
        const v2f* wr = (const v2f*)(W2 + k * 64);
#pragma unroll
        for (int c = 0; c < 32; c++) h2[c] = pkfma(xk2, wr[c], h2[c]);
    }
    __syncthreads();
#pragma unroll
    for (int c = 0; c < 32; c++) {
        ht[(2 * c + 0) * 64 + lane] = fmaxf(h2[c].x, 0.0f);
        ht[(2 * c + 1) * 64 + lane] = fmaxf(h2[c].y, 0.0f);
    }
    __syncthreads();
#pragma unroll
    for (int half = 0; half < 2; half++) {
        v2f o[32];
        const v2f* B3v = (const v2f*)(B3 + half * 64);
#pragma unroll
        for (int j = 0; j < 32; j++) o[j] = B3v[j];
        for (int k = 0; k < 64; k++) {
            float xk = ht[k * 64 + lane];
            v2f xk2 = {xk, xk};
            const v2f* wr = (const v2f*)(W3 + k * 128 + half * 64);
#pragma unroll
            for (int j = 0; j < 32; j++) o[j] = pkfma(xk2, wr[j], o[j]);
        }
#pragma unroll
        for (int j = 0; j < 32; j++) {
            float va = fmaxf(o[j].x, 0.0f);
            float vb = fmaxf(o[j].y, 0.0f);
#pragma unroll
            for (int m = 16; m >= 1; m >>= 1) {
                va = fmaxf(va, __shfl_xor(va, m));
                vb = fmaxf(vb, __shfl_xor(vb, m));
            }
            o[j].x = va; o[j].y = vb;
        }
        if (nn == 0) {
#pragma unroll
            for (int j = 0; j < 32; j++) {
                l1f[(size_t)center * 128 + half * 64 + 2 * j + 0] = o[j].x;
                l1f[(size_t)center * 128 + half * 64 + 2 * j + 1] = o[j].y;
            }
        }
    }
}

// ---------------- SA2 MLP: 131->128->128->256, max over 64 nbrs, packed fp32 ----------------
// (256, 4 waves x 32 ch) is the EMPIRICAL OPTIMUM: r5 2->4 waves = -200us;
// r16 4->8 waves = +27us (LDS-read issue doubles, pkfma:ds_read ratio halves).
// unroll 2 on k-loops (r14 tail win).
__global__ __launch_bounds__(256, 4) void sa2_kernel(const float* __restrict__ l1x, const float* __restrict__ l2x,
                                                  const float* __restrict__ l1f, const int* __restrict__ idx2,
                                                  const float* __restrict__ W1, const float* __restrict__ B1,
                                                  const float* __restrict__ W2, const float* __restrict__ B2,
                                                  const float* __restrict__ W3, const float* __restrict__ B3,
                                                  float* __restrict__ x3t) {
    __shared__ float ht[128 * 64];
    int tid = threadIdx.x;
    int w = __builtin_amdgcn_readfirstlane(tid >> 6);   // 0..3, wave-uniform -> SGPR
    int lane = tid & 63;
    int b = blockIdx.x >> 7, s = blockIdx.x & 127;
    int center = b * 128 + s;
    int ii = idx2[center * 64 + lane];
    float cx = l2x[(size_t)center * 3 + 0], cy = l2x[(size_t)center * 3 + 1], cz = l2x[(size_t)center * 3 + 2];
    const float* pr = l1x + ((size_t)b * 512 + ii) * 3;
    float px = pr[0] - cx, py = pr[1] - cy, pz = pr[2] - cz;
    const float4* frow = (const float4*)(l1f + ((size_t)b * 512 + ii) * 128);
    v2f h[16];
    {
        const v2f* B1v = (const v2f*)(B1 + w * 32);
        const v2f* w1a = (const v2f*)(W1 + 0 * 128 + w * 32);
        const v2f* w1b = (const v2f*)(W1 + 1 * 128 + w * 32);
        const v2f* w1c = (const v2f*)(W1 + 2 * 128 + w * 32);
        v2f px2 = {px, px}, py2 = {py, py}, pz2 = {pz, pz};
#pragma unroll
        for (int j = 0; j < 16; j++)
            h[j] = pkfma(pz2, w1c[j], pkfma(py2, w1b[j], pkfma(px2, w1a[j], B1v[j])));
    }
#pragma unroll 2
    for (int k4 = 0; k4 < 32; k4++) {
        float4 f = frow[k4];
        const v2f* wr = (const v2f*)(W1 + (3 + k4 * 4) * 128 + w * 32);
        v2f fx2 = {f.x, f.x}, fy2 = {f.y, f.y}, fz2 = {f.z, f.z}, fw2 = {f.w, f.w};
#pragma unroll
        for (int j = 0; j < 16; j++) {
            h[j] = pkfma(fx2, wr[j], h[j]);
            h[j] = pkfma(fy2, wr[64 + j], h[j]);
            h[j] = pkfma(fz2, wr[128 + j], h[j]);
            h[j] = pkfma(fw2, wr[192 + j], h[j]);
        }
    }
#pragma unroll
    for (int j = 0; j < 16; j++) {
        ht[(w * 32 + 2 * j + 0) * 64 + lane] = fmaxf(h[j].x, 0.0f);
        ht[(w * 32 + 2 * j + 1) * 64 + lane] = fmaxf(h[j].y, 0.0f);
    }
    __syncthreads();
    v2f h2[16];
    {
        const v2f* B2v = (const v2f*)(B2 + w * 32);
#pragma unroll
        for (int j = 0; j < 16; j++) h2[j] = B2v[j];
    }
#pragma unroll 2
    for (int k = 0; k < 128; k++) {
        float xk = ht[k * 64 + lane];
        v2f xk2 = {xk, xk};
        const v2f* wr = (const v2f*)(W2 + k * 128 + w * 32);
#pragma unroll
        for (int j = 0; j < 16; j++) h2[j] = pkfma(xk2, wr[j], h2[j]);
    }
    __syncthreads();
#pragma unroll
    for (int j = 0; j < 16; j++) {
        ht[(w * 32 + 2 * j + 0) * 64 + lane] = fmaxf(h2[j].x, 0.0f);
        ht[(w * 32 + 2 * j + 1) * 64 + lane] = fmaxf(h2[j].y, 0.0f);
    }
    __syncthreads();
#pragma unroll
    for (int half = 0; half < 2; half++) {
        v2f o[16];
        const v2f* B3v = (const v2f*)(B3 + w * 64 + half * 32);
#pragma unroll
        for (int j = 0; j < 16; j++) o[j] = B3v[j];
#pragma unroll 2
        for (int k = 0; k < 128; k++) {
            float xk = ht[k * 64 + lane];
            v2f xk2 = {xk, xk};
            const v2f* wr = (const v2f*)(W3 + k * 256 + w * 64 + half * 32);
#pragma unroll
            for (int j = 0; j < 16; j++) o[j] = pkfma(xk2, wr[j], o[j]);
        }
#pragma unroll
        for (int j = 0; j < 16; j++) {
            float va = fmaxf(o[j].x, 0.0f);
            float vb = fmaxf(o[j].y, 0.0f);
#pragma unroll
            for (int m = 32; m >= 1; m >>= 1) {
                va = fmaxf(va, __shfl_xor(va, m));
                vb = fmaxf(vb, __shfl_xor(vb, m));
            }
            o[j].x = va; o[j].y = vb;
        }
        if (lane == 0) {
#pragma unroll
            for (int j = 0; j < 16; j++) {
                x3t[(size_t)(3 + w * 64 + half * 32 + 2 * j + 0) * 2048 + center] = o[j].x;
                x3t[(size_t)(3 + w * 64 + half * 32 + 2 * j + 1) * 2048 + center] = o[j].y;
            }
        }
    }
}

// ---------------- transposed GEMM body for SA3 (packed fp32) ----------------
template<int K, int COUT, int CPT, bool MAXOUT>
__device__ __forceinline__ void gemm_t_body(const float* __restrict__ in_t,
                                            const float* __restrict__ W,
                                            const float* __restrict__ bias,
                                            float* __restrict__ outp,
                                            int bid, int lane) {
    int rw = bid & 31, cg = bid >> 5;
    int row = rw * 64 + lane;
    int cbase = cg * CPT;
    v2f acc[CPT / 2];
    const v2f* bv = (const v2f*)(bias + cbase);
#pragma unroll
    for (int j = 0; j < CPT / 2; j++) acc[j] = bv[j];
    for (int k = 0; k < K; k++) {
        float xk = in_t[(size_t)k * 2048 + row];
        v2f xk2 = {xk, xk};
        const v2f* wr = (const v2f*)(W + (size_t)k * COUT + cbase);
#pragma unroll
        for (int j = 0; j < CPT / 2; j++) acc[j] = pkfma(xk2, wr[j], acc[j]);
    }
    if (MAXOUT) {
        int b = row >> 7;
#pragma unroll
        for (int j = 0; j < CPT / 2; j++) {
            float va = fmaxf(acc[j].x, 0.0f);
            float vb = fmaxf(acc[j].y, 0.0f);
#pragma unroll
            for (int m = 32; m >= 1; m >>= 1) {
                va = fmaxf(va, __shfl_xor(va, m));
                vb = fmaxf(vb, __shfl_xor(vb, m));
            }
            if (lane == 0) {
                atomicMax((int*)(outp + (size_t)b * 1024 + cbase + 2 * j + 0), __float_as_int(va));
                atomicMax((int*)(outp + (size_t)b * 1024 + cbase + 2 * j + 1), __float_as_int(vb));
            }
        }
    } else {
#pragma unroll
        for (int j = 0; j < CPT / 2; j++) {
            outp[(size_t)(cbase + 2 * j + 0) * 2048 + row] = fmaxf(acc[j].x, 0.0f);
            outp[(size_t)(cbase + 2 * j + 1) * 2048 + row] = fmaxf(acc[j].y, 0.0f);
        }
    }
}

template<int K, int COUT, int CPT, bool MAXOUT>
__global__ __launch_bounds__(64, 4) void gemm_t_kernel(const float* __restrict__ in_t,
                                                    const float* __restrict__ W,
                                                    const float* __restrict__ bias,
                                                    float* __restrict__ outp) {
    gemm_t_body<K, COUT, CPT, MAXOUT>(in_t, W, bias, outp, blockIdx.x, threadIdx.x);
}

// gemm1 CPT=8 (blocks 0..1023) + zero-init of g (blocks 1024..1279)
__global__ __launch_bounds__(64, 4) void gemm1_zerog_kernel(const float* __restrict__ in_t,
                                                            const float* __restrict__ W,
                                                            const float* __restrict__ bias,
                                                            float* __restrict__ outp,
                                                            float* __restrict__ g) {
    if (blockIdx.x < 1024) {
        gemm_t_body<259, 256, 8, false>(in_t, W, bias, outp, blockIdx.x, threadIdx.x);
    } else {
        g[(blockIdx.x - 1024) * 64 + threadIdx.x] = 0.0f;
    }
}

// ---------------- FC heads ----------------
__global__ __launch_bounds__(512) void head_kernel(const float* __restrict__ g,
                                                   const float* __restrict__ lw1, const float* __restrict__ lb1,
                                                   const float* __restrict__ lw2, const float* __restrict__ lb2,
                                                   const float* __restrict__ fw1, const float* __restrict__ fb1,
                                                   const float* __restrict__ fw2, const float* __restrict__ fb2,
                                                   const float* __restrict__ pm, const float* __restrict__ ps,
                                                   const float* __restrict__ rm, const float* __restrict__ rs,
                                                   float* __restrict__ out) {
    __shared__ float gl[1024], a1[256], f1[512];
    int b = blockIdx.x, t = threadIdx.x;
    for (int i = t; i < 1024; i += 512) gl[i] = g[b * 1024 + i];
    __syncthreads();
    {
        float acc = fb1[t];
        for (int k = 0; k < 1024; k++) acc += gl[k] * fw1[k * 512 + t];
        f1[t] = fmaxf(acc, 0.0f);
    }
    if (t < 256) {
        float acc = lb1[t];
        for (int k = 0; k < 1024; k++) acc += gl[k] * lw1[k * 256 + t];
        a1[t] = fmaxf(acc, 0.0f);
    }
    __syncthreads();
    if (t < 2) {
        float z = lb2[t];
        for (int k = 0; k < 256; k++) z += a1[k] * lw2[k * 2 + t];
        out[b * 20 + t] = 1.0f / (1.0f + expf(-z));
    } else if (t < 20) {
        int i = t - 2;
        float z = fb2[i];
        for (int k = 0; k < 512; k++) z += f1[k] * fw2[k * 18 + i];
        float sc, mn;
        if (i < 3)       { sc = ps[i];      mn = pm[i]; }
        else if (i < 9)  { sc = rs[i - 3];  mn = rm[i - 3]; }
        else if (i < 12) { sc = ps[i - 9];  mn = pm[i - 9]; }
        else             { sc = rs[i - 12]; mn = rm[i - 12]; }
        out[b * 20 + t] = z * sc + mn;
    }
}

static inline size_t align256(size_t x) { return (x + 255) & ~(size_t)255; }

extern "C" void kernel_launch(void* const* d_in, const int* in_sizes, int n_in,
                              void* d_out, int out_size, void* d_ws, size_t ws_size,
                              hipStream_t stream) {
    const float* points = (const float*)d_in[0];
    const float* w10 = (const float*)d_in[1];  const float* b10 = (const float*)d_in[2];
    const float* w11 = (const float*)d_in[3];  const float* b11 = (const float*)d_in[4];
    const float* w12 = (const float*)d_in[5];  const float* b12 = (const float*)d_in[6];
    const float* w20 = (const float*)d_in[7];  const float* b20 = (const float*)d_in[8];
    const float* w21 = (const float*)d_in[9];  const float* b21 = (const float*)d_in[10];
    const float* w22 = (const float*)d_in[11]; const float* b22 = (const float*)d_in[12];
    const float* w30 = (const float*)d_in[13]; const float* b30 = (const float*)d_in[14];
    const float* w31 = (const float*)d_in[15]; const float* b31 = (const float*)d_in[16];
    const float* w32 = (const float*)d_in[17]; const float* b32 = (const float*)d_in[18];
    const float* lw1 = (const float*)d_in[19]; const float* lb1 = (const float*)d_in[20];
    const float* lw2 = (const float*)d_in[21]; const float* lb2 = (const float*)d_in[22];
    const float* fw1 = (const float*)d_in[23]; const float* fb1 = (const float*)d_in[24];
    const float* fw2 = (const float*)d_in[25]; const float* fb2 = (const float*)d_in[26];
    const float* pm  = (const float*)d_in[27]; const float* ps  = (const float*)d_in[28];
    const float* rm  = (const float*)d_in[29]; const float* rs  = (const float*)d_in[30];
    float* out = (float*)d_out;

    char* p = (char*)d_ws;
    float* l1x  = (float*)p; p += align256((size_t)BB * 512 * 3 * 4);
    int*   idx1 = (int*)p;   p += align256((size_t)BB * 512 * 32 * 4);
    float* l1f  = (float*)p; p += align256((size_t)BB * 512 * 128 * 4);
    float* l2x  = (float*)p; p += align256((size_t)BB * 128 * 3 * 4);
    int*   idx2 = (int*)p;   p += align256((size_t)BB * 128 * 64 * 4);
    float* x3t  = (float*)p; p += align256((size_t)259 * 2048 * 4);
    float* h1t  = (float*)p; p += align256((size_t)256 * 2048 * 4);
    float* h2t  = (float*)p; p += align256((size_t)512 * 2048 * 4);
    float* g    = (float*)p; p += align256((size_t)BB * 1024 * 4);

    const float R2A = (float)(0.2 * 0.2);
    const float R2B = (float)(0.4 * 0.4);

    fps_kernel<4096, 512, 512><<<BB, 512, 0, stream>>>(points, l1x, (float*)nullptr, 0);
    bq1_fps2_kernel<<<1040, 512, 0, stream>>>(points, l1x, l2x, x3t, idx1, R2A);
    sa1_bq2_kernel<<<6144, 64, 0, stream>>>(points, l1x, idx1, l2x, idx2, R2B,
                                            w10, b10, w11, b11, w12, b12, l1f);
    sa2_kernel<<<2048, 256, 0, stream>>>(l1x, l2x, l1f, idx2, w20, b20, w21, b21, w22, b22, x3t);
    gemm1_zerog_kernel<<<1280, 64, 0, stream>>>(x3t, w30, b30, h1t, g);
    gemm_t_kernel<256, 512, 8, false><<<2048, 64, 0, stream>>>(h1t, w31, b31, h2t);
    gemm_t_kernel<512, 1024, 8, true><<<4096, 64, 0, stream>>>(h2t, w32, b32, g);
    head_kernel<<<BB, 512, 0, stream>>>(g, lw1, lb1, lw2, lb2, fw1, fb1, fw2, fb2, pm, ps, rm, rs, out);
}